// Round 6
// baseline (5077.818 us; speedup 1.0000x reference)
//
#include <hip/hip_runtime.h>
#include <hip/hip_bf16.h>

typedef unsigned short u16;
typedef unsigned int u32;

// Problem dims
#define Bb 16
#define Tt 1024
#define Dd 1024
#define Nn 64
#define Hh 16
#define Mm (Bb*Tt)          // 16384 rows

#define TILE_M 64
#define TILE_N 64
#define TILE_K 16

struct __align__(8) u16x4 { u16 x, y, z, w; };

__device__ __forceinline__ float bf2f(u16 u) { return __uint_as_float(((u32)u) << 16); }
__device__ __forceinline__ u16 f2bf(float f) {
    __hip_bfloat16 h = __float2bfloat16(f);
    return *reinterpret_cast<u16*>(&h);
}
__device__ __forceinline__ float sigf(float x) { return 1.0f / (1.0f + expf(-x)); }

template<typename T> __device__ __forceinline__ float ldf(const T* p);
template<> __device__ __forceinline__ float ldf<float>(const float* p) { return *p; }
template<> __device__ __forceinline__ float ldf<u16>(const u16* p) { return bf2f(*p); }

template<typename T> __device__ __forceinline__ void stf(T* p, float v);
template<> __device__ __forceinline__ void stf<float>(float* p, float v) { *p = v; }
template<> __device__ __forceinline__ void stf<u16>(u16* p, float v) { *p = f2bf(v); }

// Generalized SGEMM: C[M,N] = act( A_mixed[M,K] @ B[K,N] + bias )
// A_mixed[m,k] = A[m,k] + (Aprev[m,k]-A[m,k])*mixcoef[k]   (token shift, T=1024 periodic)
// act: 0=none 1=tanh 2=sigmoid 3=decay-chain exp(-exp(-log1p(exp(-p))-0.5))
template<typename TA, typename TC>
__global__ __launch_bounds__(256)
void sgemm_mix(const TA* __restrict__ A, int lda,
               const float* __restrict__ Bw, int ldb,
               TC* __restrict__ C, int ldc,
               int N, int K,
               const float* __restrict__ mixcoef,
               const float* __restrict__ bias,
               int act)
{
    __shared__ float As[TILE_K][TILE_M + 1];
    __shared__ float Bs[TILE_K][TILE_N + 1];
    const int tid = threadIdx.x;
    const int tx = tid & 15, ty = tid >> 4;
    const int bm = blockIdx.x * TILE_M;
    const int bn = blockIdx.y * TILE_N;

    float acc[4][4] = {};

    for (int k0 = 0; k0 < K; k0 += TILE_K) {
#pragma unroll
        for (int l = 0; l < 4; ++l) {
            int idx = l * 256 + tid;
            int kk = idx & 15, mm = idx >> 4;
            int gm = bm + mm;
            int gk = k0 + kk;
            float xv = ldf<TA>(A + (size_t)gm * lda + gk);
            if (mixcoef) {
                int t = gm & (Tt - 1);
                float xp = (t == 0) ? 0.0f : ldf<TA>(A + (size_t)(gm - 1) * lda + gk);
                xv += (xp - xv) * mixcoef[gk];
            }
            As[kk][mm] = xv;
        }
#pragma unroll
        for (int l = 0; l < 4; ++l) {
            int idx = l * 256 + tid;
            int nn = idx & 63, kk = idx >> 6;
            int gn = bn + nn;
            Bs[kk][nn] = (gn < N) ? Bw[(size_t)(k0 + kk) * ldb + gn] : 0.0f;
        }
        __syncthreads();
#pragma unroll
        for (int kk = 0; kk < TILE_K; ++kk) {
            float af[4], bf[4];
#pragma unroll
            for (int i = 0; i < 4; ++i) af[i] = As[kk][ty * 4 + i];
#pragma unroll
            for (int j = 0; j < 4; ++j) bf[j] = Bs[kk][tx * 4 + j];
#pragma unroll
            for (int i = 0; i < 4; ++i)
#pragma unroll
                for (int j = 0; j < 4; ++j)
                    acc[i][j] = fmaf(af[i], bf[j], acc[i][j]);
        }
        __syncthreads();
    }

#pragma unroll
    for (int i = 0; i < 4; ++i) {
        int gm = bm + ty * 4 + i;
#pragma unroll
        for (int j = 0; j < 4; ++j) {
            int gn = bn + tx * 4 + j;
            if (gn >= N) continue;
            float v = acc[i][j];
            if (bias) v += bias[gn];
            if (act == 1) v = tanhf(v);
            else if (act == 2) v = sigf(v);
            else if (act == 3) {
                float w = -log1pf(expf(-v)) - 0.5f;
                v = expf(-expf(w));
            }
            stf<TC>(C + (size_t)gm * ldc + gn, v);
        }
    }
}

// W_o GEMM with fused relu-maxpool epilogue. A = o2 (bf16), B = W_o (f32).
// Block tile = 64 rows (all same batch b since 64|1024) x 64 cols.
// No C store: block-local column max -> relu -> atomicMax into H[b][col].
__global__ __launch_bounds__(256)
void gemm_wo_maxpool(const u16* __restrict__ A,
                     const float* __restrict__ Bw,
                     float* __restrict__ Hbuf)
{
    __shared__ float As[TILE_K][TILE_M + 1];
    __shared__ float Bs[TILE_K][TILE_N + 1];
    const int tid = threadIdx.x;
    const int tx = tid & 15, ty = tid >> 4;
    const int bm = blockIdx.x * TILE_M;
    const int bn = blockIdx.y * TILE_N;

    float acc[4][4] = {};

    for (int k0 = 0; k0 < Dd; k0 += TILE_K) {
#pragma unroll
        for (int l = 0; l < 4; ++l) {
            int idx = l * 256 + tid;
            int kk = idx & 15, mm = idx >> 4;
            As[kk][mm] = bf2f(A[(size_t)(bm + mm) * Dd + k0 + kk]);
        }
#pragma unroll
        for (int l = 0; l < 4; ++l) {
            int idx = l * 256 + tid;
            int nn = idx & 63, kk = idx >> 6;
            Bs[kk][nn] = Bw[(size_t)(k0 + kk) * Dd + bn + nn];
        }
        __syncthreads();
#pragma unroll
        for (int kk = 0; kk < TILE_K; ++kk) {
            float af[4], bf[4];
#pragma unroll
            for (int i = 0; i < 4; ++i) af[i] = As[kk][ty * 4 + i];
#pragma unroll
            for (int j = 0; j < 4; ++j) bf[j] = Bs[kk][tx * 4 + j];
#pragma unroll
            for (int i = 0; i < 4; ++i)
#pragma unroll
                for (int j = 0; j < 4; ++j)
                    acc[i][j] = fmaf(af[i], bf[j], acc[i][j]);
        }
        __syncthreads();
    }

    // column-max over this block's 64 rows
    __shared__ float smax[16][TILE_N + 1];
#pragma unroll
    for (int j = 0; j < 4; ++j) {
        float m = fmaxf(fmaxf(acc[0][j], acc[1][j]), fmaxf(acc[2][j], acc[3][j]));
        smax[ty][tx * 4 + j] = m;
    }
    __syncthreads();
    if (tid < TILE_N) {
        float m = smax[0][tid];
#pragma unroll
        for (int q = 1; q < 16; ++q) m = fmaxf(m, smax[q][tid]);
        m = fmaxf(m, 0.0f);   // relu
        int b = bm >> 10;     // batch of all 64 rows
        atomicMax((u32*)&Hbuf[b * Dd + bn + tid], __float_as_uint(m));
    }
}

// kk = normalize_per_head(k*k_k); k <- k*(1+(a-1)*k_a); ab <- kk*a  (b vector)
__global__ __launch_bounds__(256)
void ew_kv_kernel(u16* __restrict__ kbuf, u16* __restrict__ abuf,
                  u16* __restrict__ kkbuf,
                  const float* __restrict__ k_k, const float* __restrict__ k_a)
{
    const int m = blockIdx.x;
    const int tid = threadIdx.x;
    const int c0 = tid * 4;
    const size_t base = (size_t)m * Dd + c0;
    u16x4 kv4 = *(const u16x4*)(kbuf + base);
    u16x4 av4 = *(const u16x4*)(abuf + base);
    float4 kkc = *(const float4*)(k_k + c0);
    float4 kac = *(const float4*)(k_a + c0);

    float kin[4] = {bf2f(kv4.x), bf2f(kv4.y), bf2f(kv4.z), bf2f(kv4.w)};
    float ain[4] = {bf2f(av4.x), bf2f(av4.y), bf2f(av4.z), bf2f(av4.w)};
    float kkc4[4] = {kkc.x, kkc.y, kkc.z, kkc.w};
    float kac4[4] = {kac.x, kac.y, kac.z, kac.w};

    float kr[4];
#pragma unroll
    for (int l = 0; l < 4; ++l) kr[l] = kin[l] * kkc4[l];
    float ss = kr[0]*kr[0] + kr[1]*kr[1] + kr[2]*kr[2] + kr[3]*kr[3];
#pragma unroll
    for (int mask = 1; mask < 16; mask <<= 1) ss += __shfl_xor(ss, mask);
    float inv = 1.0f / fmaxf(sqrtf(ss), 1e-12f);

    u16x4 kkv, kmv, bvv;
    u16* kkp = &kkv.x; u16* kmp = &kmv.x; u16* bvp = &bvv.x;
#pragma unroll
    for (int l = 0; l < 4; ++l) {
        float kkf = kr[l] * inv;
        kkp[l] = f2bf(kkf);
        kmp[l] = f2bf(kin[l] * (1.0f + (ain[l] - 1.0f) * kac4[l]));
        bvp[l] = f2bf(kkf * ain[l]);
    }
    *(u16x4*)(kkbuf + base) = kkv;
    *(u16x4*)(kbuf  + base) = kmv;
    *(u16x4*)(abuf  + base) = bvv;
}

// RWKV7 scan: one block per (b,h). 256 threads, thread (i,q) owns S[i][16q..16q+16)
__global__ __launch_bounds__(256)
void scan_kernel(const u16* __restrict__ rb, const u16* __restrict__ db,
                 const u16* __restrict__ kb, const u16* __restrict__ vb,
                 const u16* __restrict__ kkb, const u16* __restrict__ bvb,
                 u16* __restrict__ ob)
{
    const int blk = blockIdx.x;
    const int batch = blk >> 4, head = blk & 15;
    const int tid = threadIdx.x;
    const int q = tid & 3, i = tid >> 2;
    const int j0 = q * 16;
    const int g = tid >> 6, j = tid & 63;

    __shared__ float sh[2][6][64];
    float S[16];
#pragma unroll
    for (int jj = 0; jj < 16; ++jj) S[jj] = 0.0f;

    const size_t rowbase = (size_t)batch * Tt * Dd + head * Nn;

    // prologue: stage t=0
    {
        size_t off = rowbase + j;
        float l0 = (g == 0) ? bf2f(rb[off]) : (g == 1) ? bf2f(db[off])
                 : (g == 2) ? bf2f(kb[off]) : bf2f(vb[off]);
        sh[0][g][j] = l0;
        if (tid < 128) sh[0][4 + g][j] = (g == 0) ? bf2f(kkb[off]) : bf2f(bvb[off]);
    }
    __syncthreads();

    int cur = 0;
    for (int t = 0; t < Tt; ++t) {
        // prefetch t+1
        float l0 = 0.0f, l1 = 0.0f;
        if (t + 1 < Tt) {
            size_t off = rowbase + (size_t)(t + 1) * Dd + j;
            l0 = (g == 0) ? bf2f(rb[off]) : (g == 1) ? bf2f(db[off])
               : (g == 2) ? bf2f(kb[off]) : bf2f(vb[off]);
            if (tid < 128) l1 = (g == 0) ? bf2f(kkb[off]) : bf2f(bvb[off]);
        }

        // sa_i = sum_j S[i][j] * (-kk[j])   (old S)
        float sa = 0.0f;
#pragma unroll
        for (int jj = 0; jj < 16; ++jj) sa = fmaf(S[jj], sh[cur][4][j0 + jj], sa);
        sa = -sa;
        sa += __shfl_xor(sa, 1);
        sa += __shfl_xor(sa, 2);

        float vi = sh[cur][3][i];
        float op = 0.0f;
#pragma unroll
        for (int jj = 0; jj < 16; ++jj) {
            float Sv = S[jj];
            Sv = Sv * sh[cur][1][j0 + jj];            // * decay_j
            Sv = fmaf(sa, sh[cur][5][j0 + jj], Sv);   // + sa_i * b_j
            Sv = fmaf(vi, sh[cur][2][j0 + jj], Sv);   // + v_i * k_j
            S[jj] = Sv;
            op = fmaf(Sv, sh[cur][0][j0 + jj], op);   // o_i += S * r_j
        }
        op += __shfl_xor(op, 1);
        op += __shfl_xor(op, 2);
        if (q == 0) ob[rowbase + (size_t)t * Dd + i] = f2bf(op);

        __syncthreads();
        if (t + 1 < Tt) {
            sh[cur ^ 1][g][j] = l0;
            if (tid < 128) sh[cur ^ 1][4 + g][j] = l1;
        }
        __syncthreads();
        cur ^= 1;
    }
}

// GroupNorm + bonus + gate: o2 = (GN(o)*gn_w+gn_b + (sum_j r*k*r_k)*v) * g
__global__ __launch_bounds__(256)
void gn_kernel(const u16* __restrict__ ob, const u16* __restrict__ rb,
               const u16* __restrict__ kb, const u16* __restrict__ vb,
               const u16* __restrict__ gb,
               const float* __restrict__ gn_w, const float* __restrict__ gn_b,
               const float* __restrict__ r_k, u16* __restrict__ o2)
{
    const int m = blockIdx.x;
    const int tid = threadIdx.x;
    const int c0 = tid * 4;
    const int h = tid >> 4;
    const int jh = c0 & 63;
    const size_t base = (size_t)m * Dd + c0;

    u16x4 ov4 = *(const u16x4*)(ob + base);
    u16x4 rv4 = *(const u16x4*)(rb + base);
    u16x4 kv4 = *(const u16x4*)(kb + base);
    u16x4 vv4 = *(const u16x4*)(vb + base);
    u16x4 gv4 = *(const u16x4*)(gb + base);
    float4 rkc = *(const float4*)(r_k + h * 64 + jh);

    float ovv[4] = {bf2f(ov4.x), bf2f(ov4.y), bf2f(ov4.z), bf2f(ov4.w)};
    float rv[4] = {bf2f(rv4.x), bf2f(rv4.y), bf2f(rv4.z), bf2f(rv4.w)};
    float kv[4] = {bf2f(kv4.x), bf2f(kv4.y), bf2f(kv4.z), bf2f(kv4.w)};
    float vv[4] = {bf2f(vv4.x), bf2f(vv4.y), bf2f(vv4.z), bf2f(vv4.w)};
    float gv[4] = {bf2f(gv4.x), bf2f(gv4.y), bf2f(gv4.z), bf2f(gv4.w)};
    float rk4[4] = {rkc.x, rkc.y, rkc.z, rkc.w};

    float s1 = ovv[0] + ovv[1] + ovv[2] + ovv[3];
    float s2 = ovv[0]*ovv[0] + ovv[1]*ovv[1] + ovv[2]*ovv[2] + ovv[3]*ovv[3];
    float sb = rv[0]*kv[0]*rk4[0] + rv[1]*kv[1]*rk4[1] + rv[2]*kv[2]*rk4[2] + rv[3]*kv[3]*rk4[3];
#pragma unroll
    for (int mask = 1; mask < 16; mask <<= 1) {
        s1 += __shfl_xor(s1, mask);
        s2 += __shfl_xor(s2, mask);
        sb += __shfl_xor(sb, mask);
    }
    float mu = s1 * (1.0f / 64.0f);
    float var = s2 * (1.0f / 64.0f) - mu * mu;
    float rstd = rsqrtf(var + 6.4e-4f);

    float4 gwv = *(const float4*)(gn_w + c0);
    float4 gbv = *(const float4*)(gn_b + c0);
    float gw4[4] = {gwv.x, gwv.y, gwv.z, gwv.w};
    float gb4[4] = {gbv.x, gbv.y, gbv.z, gbv.w};

    u16x4 outv; u16* op = &outv.x;
#pragma unroll
    for (int l = 0; l < 4; ++l) {
        float v = (((ovv[l] - mu) * rstd) * gw4[l] + gb4[l] + sb * vv[l]) * gv[l];
        op[l] = f2bf(v);
    }
    *(u16x4*)(o2 + base) = outv;
}

__global__ __launch_bounds__(256)
void zero_kernel(float* __restrict__ p, int n)
{
    int i = blockIdx.x * 256 + threadIdx.x;
    if (i < n) p[i] = 0.0f;
}

// out[b,c] = b_cls[c] + sum_d h[b,d]*W_cls[d,c]   (grid=32 blocks, one per (b,c))
__global__ __launch_bounds__(256)
void cls_kernel(const float* __restrict__ hp, const float* __restrict__ Wc,
                const float* __restrict__ bc, float* __restrict__ out)
{
    const int p = blockIdx.x;
    const int b = p >> 1, c = p & 1;
    const int tid = threadIdx.x;
    float partial = 0.0f;
    for (int d = tid; d < Dd; d += 256)
        partial = fmaf(hp[b * Dd + d], Wc[d * 2 + c], partial);
    __shared__ float red[256];
    red[tid] = partial;
    __syncthreads();
    for (int s = 128; s > 0; s >>= 1) {
        if (tid < s) red[tid] += red[tid + s];
        __syncthreads();
    }
    if (tid == 0) out[b * 2 + c] = red[0] + bc[c];
}

extern "C" void kernel_launch(void* const* d_in, const int* in_sizes, int n_in,
                              void* d_out, int out_size, void* d_ws, size_t ws_size,
                              hipStream_t stream)
{
    const float* x    = (const float*)d_in[0];
    const float* x_r  = (const float*)d_in[1];
    const float* x_w  = (const float*)d_in[2];
    const float* x_k  = (const float*)d_in[3];
    const float* x_v  = (const float*)d_in[4];
    const float* x_a  = (const float*)d_in[5];
    const float* x_g  = (const float*)d_in[6];
    const float* W_r  = (const float*)d_in[7];
    const float* W_k  = (const float*)d_in[8];
    const float* W_v  = (const float*)d_in[9];
    const float* W_o  = (const float*)d_in[10];
    const float* w0   = (const float*)d_in[11];
    const float* w1   = (const float*)d_in[12];
    const float* w2   = (const float*)d_in[13];
    const float* a0   = (const float*)d_in[14];
    const float* a1   = (const float*)d_in[15];
    const float* a2   = (const float*)d_in[16];
    const float* g1   = (const float*)d_in[17];
    const float* g2   = (const float*)d_in[18];
    const float* k_k  = (const float*)d_in[19];
    const float* k_a  = (const float*)d_in[20];
    const float* r_k  = (const float*)d_in[21];
    const float* gn_w = (const float*)d_in[22];
    const float* gn_b = (const float*)d_in[23];
    const float* Wcls = (const float*)d_in[24];
    const float* bcls = (const float*)d_in[25];
    float* out = (float*)d_out;

    const size_t MD = (size_t)Mm * Dd;
    char* w = (char*)d_ws;
    u16* bufR  = (u16*)w;  w += MD * 2;     // r (bf16)                 32MB
    u16* bufK  = (u16*)w;  w += MD * 2;     // k -> k_mod (bf16)        32MB
    u16* bufV  = (u16*)w;  w += MD * 2;     // v (bf16)                 32MB
    u16* bufAB = (u16*)w;  w += MD * 2;     // a -> b=kk*a (bf16)       32MB
    u16* bufKK = (u16*)w;  w += MD * 2;     // kk (bf16); later o2      32MB
    u16* bufWd = (u16*)w;  w += MD * 2;     // decay (bf16); later g    32MB
    u16* bufO  = (u16*)w;  w += MD * 2;     // scan out (bf16)          32MB
    float* bufTW = (float*)w; w += (size_t)Mm * 64 * 4;   // 4MB
    float* bufTA = (float*)w; w += (size_t)Mm * 64 * 4;   // 4MB
    float* bufTG = (float*)w; w += (size_t)Mm * 160 * 4;  // 10MB
    float* bufH  = (float*)w; w += (size_t)Bb * Dd * 4;   // 64KB
    u16* bufG  = bufWd;         // g overlays decay slot (after scan)
    u16* bufO2 = bufKK;         // o2 overlays kk slot (after scan)

    dim3 blk(256);
    dim3 gBig(Mm / TILE_M, Dd / TILE_N);   // (256,16)
    dim3 g64(Mm / TILE_M, 1);
    dim3 g160(Mm / TILE_M, 3);

    // big projections with token-shift mixing -> bf16
    sgemm_mix<float, u16><<<gBig, blk, 0, stream>>>(x, Dd, W_r, Dd, bufR, Dd, Dd, Dd, x_r, nullptr, 0);
    sgemm_mix<float, u16><<<gBig, blk, 0, stream>>>(x, Dd, W_k, Dd, bufK, Dd, Dd, Dd, x_k, nullptr, 0);
    sgemm_mix<float, u16><<<gBig, blk, 0, stream>>>(x, Dd, W_v, Dd, bufV, Dd, Dd, Dd, x_v, nullptr, 0);
    // LoRA stage 1 (fp32 temps)
    sgemm_mix<float, float><<<g64,  blk, 0, stream>>>(x, Dd, w1, 64,  bufTW, 64,  64,  Dd, x_w, nullptr, 1);
    sgemm_mix<float, float><<<g64,  blk, 0, stream>>>(x, Dd, a1, 64,  bufTA, 64,  64,  Dd, x_a, nullptr, 0);
    sgemm_mix<float, float><<<g160, blk, 0, stream>>>(x, Dd, g1, 160, bufTG, 160, 160, Dd, x_g, nullptr, 2);
    // LoRA stage 2: decay (bf16), a (bf16)
    sgemm_mix<float, u16><<<gBig, blk, 0, stream>>>(bufTW, 64, w2, Dd, bufWd, Dd, Dd, 64, nullptr, w0, 3);
    sgemm_mix<float, u16><<<gBig, blk, 0, stream>>>(bufTA, 64, a2, Dd, bufAB, Dd, Dd, 64, nullptr, a0, 2);
    // kk / k-mod / b
    ew_kv_kernel<<<Mm, blk, 0, stream>>>(bufK, bufAB, bufKK, k_k, k_a);
    // scan (consumes decay slot)
    scan_kernel<<<Bb * Hh, blk, 0, stream>>>(bufR, bufWd, bufK, bufV, bufKK, bufAB, bufO);
    // gate g -> overlays decay slot (safe: scan done)
    sgemm_mix<float, u16><<<gBig, blk, 0, stream>>>(bufTG, 160, g2, Dd, bufG, Dd, Dd, 160, nullptr, nullptr, 0);
    // GN + bonus + gate -> o2 (overlays kk slot)
    gn_kernel<<<Mm, blk, 0, stream>>>(bufO, bufR, bufK, bufV, bufG, gn_w, gn_b, r_k, bufO2);
    // zero H, then W_o GEMM with fused relu-maxpool
    zero_kernel<<<(Bb * Dd + 255) / 256, blk, 0, stream>>>(bufH, Bb * Dd);
    gemm_wo_maxpool<<<gBig, blk, 0, stream>>>(bufO2, W_o, bufH);
    // classifier
    cls_kernel<<<32, blk, 0, stream>>>(bufH, Wcls, bcls, out);
}

// Round 8
// 2098.062 us; speedup vs baseline: 2.4202x; 2.4202x over previous
//
#include <hip/hip_runtime.h>
#include <hip/hip_bf16.h>

typedef unsigned short u16;
typedef unsigned int u32;

#define Bb 16
#define Tt 1024
#define Dd 1024
#define Nn 64
#define Hh 16
#define Mm (Bb*Tt)

#define TILE_M 64
#define TILE_N 64
#define TILE_K 16

typedef float f32x4 __attribute__((ext_vector_type(4)));
typedef short s16x8 __attribute__((ext_vector_type(8)));

struct __align__(8) u16x4s { u16 x, y, z, w; };

__device__ __forceinline__ float bf2f(u16 u) { return __uint_as_float(((u32)u) << 16); }
__device__ __forceinline__ u16 f2bf(float f) {
    __hip_bfloat16 h = __float2bfloat16(f);
    return *reinterpret_cast<u16*>(&h);
}
__device__ __forceinline__ float sigf(float x) { return 1.0f / (1.0f + expf(-x)); }

template<typename T> __device__ __forceinline__ float ldf(const T* p);
template<> __device__ __forceinline__ float ldf<float>(const float* p) { return *p; }
template<> __device__ __forceinline__ float ldf<u16>(const u16* p) { return bf2f(*p); }

// ---------------- mix6: token-shift for all six branches, fp32 -> bf16 ----------------
__global__ __launch_bounds__(256)
void mix6_kernel(const float* __restrict__ x,
                 const float* __restrict__ cr, const float* __restrict__ ck,
                 const float* __restrict__ cv, const float* __restrict__ cw,
                 const float* __restrict__ ca, const float* __restrict__ cg,
                 u16* __restrict__ o0, u16* __restrict__ o1, u16* __restrict__ o2,
                 u16* __restrict__ o3, u16* __restrict__ o4, u16* __restrict__ o5)
{
    const int m = blockIdx.x;
    const int c0 = threadIdx.x * 4;
    const size_t base = (size_t)m * Dd + c0;
    float4 xc = *(const float4*)(x + base);
    float4 xp = make_float4(0.f, 0.f, 0.f, 0.f);
    if (m & (Tt - 1)) xp = *(const float4*)(x + base - Dd);
    float dx[4] = {xp.x - xc.x, xp.y - xc.y, xp.z - xc.z, xp.w - xc.w};
    float xv[4] = {xc.x, xc.y, xc.z, xc.w};
    const float* cfs[6] = {cr, ck, cv, cw, ca, cg};
    u16* outs[6] = {o0, o1, o2, o3, o4, o5};
#pragma unroll
    for (int s = 0; s < 6; ++s) {
        float4 cf = *(const float4*)(cfs[s] + c0);
        float c4[4] = {cf.x, cf.y, cf.z, cf.w};
        u16x4s ov;
        u16* op = &ov.x;
#pragma unroll
        for (int l = 0; l < 4; ++l) op[l] = f2bf(fmaf(dx[l], c4[l], xv[l]));
        *(u16x4s*)(outs[s] + base) = ov;
    }
}

// ---------------- small fp32-compute GEMM for LoRA stage-1 (bf16 A, fp32 B) ----------------
// act: 0=none 1=tanh 2=sigmoid
__global__ __launch_bounds__(256)
void sgemm_small(const u16* __restrict__ A, int lda,
                 const float* __restrict__ Bw, int ldb,
                 u16* __restrict__ C, int ldc,
                 int N, int K, int act)
{
    __shared__ float As[TILE_K][TILE_M + 1];
    __shared__ float Bs[TILE_K][TILE_N + 1];
    const int tid = threadIdx.x;
    const int tx = tid & 15, ty = tid >> 4;
    const int bm = blockIdx.x * TILE_M;
    const int bn = blockIdx.y * TILE_N;

    float acc[4][4] = {};

    for (int k0 = 0; k0 < K; k0 += TILE_K) {
#pragma unroll
        for (int l = 0; l < 4; ++l) {
            int idx = l * 256 + tid;
            int kk = idx & 15, mm = idx >> 4;
            As[kk][mm] = bf2f(A[(size_t)(bm + mm) * lda + k0 + kk]);
        }
#pragma unroll
        for (int l = 0; l < 4; ++l) {
            int idx = l * 256 + tid;
            int nn = idx & 63, kk = idx >> 6;
            int gn = bn + nn;
            Bs[kk][nn] = (gn < N) ? Bw[(size_t)(k0 + kk) * ldb + gn] : 0.0f;
        }
        __syncthreads();
#pragma unroll
        for (int kk = 0; kk < TILE_K; ++kk) {
            float af[4], bf[4];
#pragma unroll
            for (int i = 0; i < 4; ++i) af[i] = As[kk][ty * 4 + i];
#pragma unroll
            for (int j = 0; j < 4; ++j) bf[j] = Bs[kk][tx * 4 + j];
#pragma unroll
            for (int i = 0; i < 4; ++i)
#pragma unroll
                for (int j = 0; j < 4; ++j)
                    acc[i][j] = fmaf(af[i], bf[j], acc[i][j]);
        }
        __syncthreads();
    }

#pragma unroll
    for (int i = 0; i < 4; ++i) {
        int gm = bm + ty * 4 + i;
#pragma unroll
        for (int j = 0; j < 4; ++j) {
            int gn = bn + tx * 4 + j;
            if (gn >= N) continue;
            float v = acc[i][j];
            if (act == 1) v = tanhf(v);
            else if (act == 2) v = sigf(v);
            C[(size_t)gm * ldc + gn] = f2bf(v);
        }
    }
}

// ---------------- MFMA GEMM: C[M,1024] = act(A[M,K](bf16) @ W[K,1024](f32) + bias) ----------------
// 128x128 tile, BK=32, 4 waves (2x2), mfma_f32_16x16x32_bf16.
// As[128][40] row-major (pad->80B stride, <=2-way banks); Bs[128][40] holds W^T tile (Bs[n][k]).
template<int ACT, bool HAS_BIAS>
__global__ __launch_bounds__(256)
void gemm_mfma(const u16* __restrict__ A, int lda,
               const float* __restrict__ W,
               const float* __restrict__ bias,
               u16* __restrict__ C, int K)
{
    __shared__ u16 As[128][40];
    __shared__ u16 Bs[128][40];
    const int tid = threadIdx.x;
    const int bm = blockIdx.x * 128, bn = blockIdx.y * 128;
    const int lane = tid & 63, w = tid >> 6;
    const int wr = w >> 1, wc = w & 1;
    const int lr = lane & 15, kg = lane >> 4;

    f32x4 acc[4][4];
#pragma unroll
    for (int m = 0; m < 4; ++m)
#pragma unroll
        for (int n = 0; n < 4; ++n) acc[m][n] = (f32x4){0.f, 0.f, 0.f, 0.f};

    for (int k0 = 0; k0 < K; k0 += 32) {
        // stage A: 128 rows x 32 k (bf16, direct copy)
        {
            int row = tid >> 2, part = tid & 3;
            *(s16x8*)&As[row][part * 8] =
                *(const s16x8*)(A + (size_t)(bm + row) * lda + k0 + part * 8);
            row += 64;
            *(s16x8*)&As[row][part * 8] =
                *(const s16x8*)(A + (size_t)(bm + row) * lda + k0 + part * 8);
        }
        // stage B transposed: Bs[n][k] = bf16(W[k0+k][bn+n])
        {
            int n4 = (tid & 31) * 4;
            int kp = tid >> 5;
#pragma unroll
            for (int it = 0; it < 2; ++it) {
                int k = 2 * (kp + it * 8);
                const float* wp = W + (size_t)(k0 + k) * 1024 + bn + n4;
                float4 wa = *(const float4*)wp;
                float4 wb = *(const float4*)(wp + 1024);
                u32 p0 = (u32)f2bf(wa.x) | ((u32)f2bf(wb.x) << 16);
                u32 p1 = (u32)f2bf(wa.y) | ((u32)f2bf(wb.y) << 16);
                u32 p2 = (u32)f2bf(wa.z) | ((u32)f2bf(wb.z) << 16);
                u32 p3 = (u32)f2bf(wa.w) | ((u32)f2bf(wb.w) << 16);
                *(u32*)&Bs[n4 + 0][k] = p0;
                *(u32*)&Bs[n4 + 1][k] = p1;
                *(u32*)&Bs[n4 + 2][k] = p2;
                *(u32*)&Bs[n4 + 3][k] = p3;
            }
        }
        __syncthreads();
        s16x8 af[4], bfr[4];
#pragma unroll
        for (int m = 0; m < 4; ++m)
            af[m] = *(const s16x8*)&As[wr * 64 + m * 16 + lr][kg * 8];
#pragma unroll
        for (int n = 0; n < 4; ++n)
            bfr[n] = *(const s16x8*)&Bs[wc * 64 + n * 16 + lr][kg * 8];
#pragma unroll
        for (int m = 0; m < 4; ++m)
#pragma unroll
            for (int n = 0; n < 4; ++n)
                acc[m][n] = __builtin_amdgcn_mfma_f32_16x16x32_bf16(af[m], bfr[n], acc[m][n], 0, 0, 0);
        __syncthreads();
    }

    // epilogue: D[row=(lane>>4)*4+r][col=lane&15] per fragment (m89 layout)
#pragma unroll
    for (int n = 0; n < 4; ++n) {
        int col = bn + wc * 64 + n * 16 + lr;
        float bv = HAS_BIAS ? bias[col] : 0.0f;
#pragma unroll
        for (int m = 0; m < 4; ++m) {
            int row0 = bm + wr * 64 + m * 16 + kg * 4;
#pragma unroll
            for (int r = 0; r < 4; ++r) {
                float v = acc[m][n][r] + bv;
                if (ACT == 2) v = sigf(v);
                else if (ACT == 3) {
                    float ww = -log1pf(expf(-v)) - 0.5f;
                    v = expf(-expf(ww));
                }
                C[(size_t)(row0 + r) * 1024 + col] = f2bf(v);
            }
        }
    }
}

// ---------------- W_o MFMA GEMM with fused relu-colmax -> atomicMax ----------------
__global__ __launch_bounds__(256)
void gemm_wo_mfma(const u16* __restrict__ A,
                  const float* __restrict__ W,
                  float* __restrict__ Hbuf)
{
    __shared__ u16 As[128][40];
    __shared__ u16 Bs[128][40];
    const int tid = threadIdx.x;
    const int bm = blockIdx.x * 128, bn = blockIdx.y * 128;
    const int lane = tid & 63, w = tid >> 6;
    const int wr = w >> 1, wc = w & 1;
    const int lr = lane & 15, kg = lane >> 4;

    f32x4 acc[4][4];
#pragma unroll
    for (int m = 0; m < 4; ++m)
#pragma unroll
        for (int n = 0; n < 4; ++n) acc[m][n] = (f32x4){0.f, 0.f, 0.f, 0.f};

    for (int k0 = 0; k0 < 1024; k0 += 32) {
        {
            int row = tid >> 2, part = tid & 3;
            *(s16x8*)&As[row][part * 8] =
                *(const s16x8*)(A + (size_t)(bm + row) * 1024 + k0 + part * 8);
            row += 64;
            *(s16x8*)&As[row][part * 8] =
                *(const s16x8*)(A + (size_t)(bm + row) * 1024 + k0 + part * 8);
        }
        {
            int n4 = (tid & 31) * 4;
            int kp = tid >> 5;
#pragma unroll
            for (int it = 0; it < 2; ++it) {
                int k = 2 * (kp + it * 8);
                const float* wp = W + (size_t)(k0 + k) * 1024 + bn + n4;
                float4 wa = *(const float4*)wp;
                float4 wb = *(const float4*)(wp + 1024);
                *(u32*)&Bs[n4 + 0][k] = (u32)f2bf(wa.x) | ((u32)f2bf(wb.x) << 16);
                *(u32*)&Bs[n4 + 1][k] = (u32)f2bf(wa.y) | ((u32)f2bf(wb.y) << 16);
                *(u32*)&Bs[n4 + 2][k] = (u32)f2bf(wa.z) | ((u32)f2bf(wb.z) << 16);
                *(u32*)&Bs[n4 + 3][k] = (u32)f2bf(wa.w) | ((u32)f2bf(wb.w) << 16);
            }
        }
        __syncthreads();
        s16x8 af[4], bfr[4];
#pragma unroll
        for (int m = 0; m < 4; ++m)
            af[m] = *(const s16x8*)&As[wr * 64 + m * 16 + lr][kg * 8];
#pragma unroll
        for (int n = 0; n < 4; ++n)
            bfr[n] = *(const s16x8*)&Bs[wc * 64 + n * 16 + lr][kg * 8];
#pragma unroll
        for (int m = 0; m < 4; ++m)
#pragma unroll
            for (int n = 0; n < 4; ++n)
                acc[m][n] = __builtin_amdgcn_mfma_f32_16x16x32_bf16(af[m], bfr[n], acc[m][n], 0, 0, 0);
        __syncthreads();
    }

    const int b = bm >> 10;
#pragma unroll
    for (int n = 0; n < 4; ++n) {
        float mv = -1e30f;
#pragma unroll
        for (int m = 0; m < 4; ++m)
#pragma unroll
            for (int r = 0; r < 4; ++r) mv = fmaxf(mv, acc[m][n][r]);
        mv = fmaxf(mv, __shfl_xor(mv, 16));
        mv = fmaxf(mv, __shfl_xor(mv, 32));
        mv = fmaxf(mv, 0.0f);
        if (lane < 16) {
            int col = bn + wc * 64 + n * 16 + lr;
            atomicMax((u32*)&Hbuf[b * Dd + col], __float_as_uint(mv));
        }
    }
}

// ---------------- kk / k-mod / b ----------------
__global__ __launch_bounds__(256)
void ew_kv_kernel(u16* __restrict__ kbuf, u16* __restrict__ abuf,
                  u16* __restrict__ kkbuf,
                  const float* __restrict__ k_k, const float* __restrict__ k_a)
{
    const int m = blockIdx.x;
    const int tid = threadIdx.x;
    const int c0 = tid * 4;
    const size_t base = (size_t)m * Dd + c0;
    u16x4s kv4 = *(const u16x4s*)(kbuf + base);
    u16x4s av4 = *(const u16x4s*)(abuf + base);
    float4 kkc = *(const float4*)(k_k + c0);
    float4 kac = *(const float4*)(k_a + c0);

    float kin[4] = {bf2f(kv4.x), bf2f(kv4.y), bf2f(kv4.z), bf2f(kv4.w)};
    float ain[4] = {bf2f(av4.x), bf2f(av4.y), bf2f(av4.z), bf2f(av4.w)};
    float kkc4[4] = {kkc.x, kkc.y, kkc.z, kkc.w};
    float kac4[4] = {kac.x, kac.y, kac.z, kac.w};

    float kr[4];
#pragma unroll
    for (int l = 0; l < 4; ++l) kr[l] = kin[l] * kkc4[l];
    float ss = kr[0]*kr[0] + kr[1]*kr[1] + kr[2]*kr[2] + kr[3]*kr[3];
#pragma unroll
    for (int mask = 1; mask < 16; mask <<= 1) ss += __shfl_xor(ss, mask);
    float inv = 1.0f / fmaxf(sqrtf(ss), 1e-12f);

    u16x4s kkv, kmv, bvv;
    u16* kkp = &kkv.x; u16* kmp = &kmv.x; u16* bvp = &bvv.x;
#pragma unroll
    for (int l = 0; l < 4; ++l) {
        float kkf = kr[l] * inv;
        kkp[l] = f2bf(kkf);
        kmp[l] = f2bf(kin[l] * (1.0f + (ain[l] - 1.0f) * kac4[l]));
        bvp[l] = f2bf(kkf * ain[l]);
    }
    *(u16x4s*)(kkbuf + base) = kkv;
    *(u16x4s*)(kbuf  + base) = kmv;
    *(u16x4s*)(abuf  + base) = bvv;
}

// ---------------- RWKV7 scan: float4 LDS reads, single barrier per step ----------------
__global__ __launch_bounds__(256)
void scan_kernel(const u16* __restrict__ rb, const u16* __restrict__ db,
                 const u16* __restrict__ kb, const u16* __restrict__ vb,
                 const u16* __restrict__ kkb, const u16* __restrict__ bvb,
                 u16* __restrict__ ob)
{
    const int blk = blockIdx.x;
    const int batch = blk >> 4, head = blk & 15;
    const int tid = threadIdx.x;
    const int q = tid & 3, i = tid >> 2;
    const int j0 = q * 16;
    const int g = tid >> 6, j = tid & 63;

    __shared__ float sh[2][6][64];
    float S[16];
#pragma unroll
    for (int jj = 0; jj < 16; ++jj) S[jj] = 0.0f;

    const size_t rowbase = (size_t)batch * Tt * Dd + head * Nn;

    {
        size_t off = rowbase + j;
        float l0 = (g == 0) ? bf2f(rb[off]) : (g == 1) ? bf2f(db[off])
                 : (g == 2) ? bf2f(kb[off]) : bf2f(vb[off]);
        sh[0][g][j] = l0;
        if (tid < 128) sh[0][4 + g][j] = (g == 0) ? bf2f(kkb[off]) : bf2f(bvb[off]);
    }
    __syncthreads();

    int c = 0;
    for (int t = 0; t < Tt; ++t) {
        float l0 = 0.0f, l1 = 0.0f;
        if (t + 1 < Tt) {
            size_t off = rowbase + (size_t)(t + 1) * Dd + j;
            l0 = (g == 0) ? bf2f(rb[off]) : (g == 1) ? bf2f(db[off])
               : (g == 2) ? bf2f(kb[off]) : bf2f(vb[off]);
            if (tid < 128) l1 = (g == 0) ? bf2f(kkb[off]) : bf2f(bvb[off]);
        }

        float rv[16], dec[16], kv[16], kkv[16], bv[16];
#pragma unroll
        for (int u = 0; u < 4; ++u) {
            *(float4*)&rv[u*4]  = *(const float4*)&sh[c][0][j0 + u*4];
            *(float4*)&dec[u*4] = *(const float4*)&sh[c][1][j0 + u*4];
            *(float4*)&kv[u*4]  = *(const float4*)&sh[c][2][j0 + u*4];
            *(float4*)&kkv[u*4] = *(const float4*)&sh[c][4][j0 + u*4];
            *(float4*)&bv[u*4]  = *(const float4*)&sh[c][5][j0 + u*4];
        }
        float vi = sh[c][3][i];

        float sa = 0.0f;
#pragma unroll
        for (int jj = 0; jj < 16; ++jj) sa = fmaf(S[jj], kkv[jj], sa);
        sa = -sa;
        sa += __shfl_xor(sa, 1);
        sa += __shfl_xor(sa, 2);

        float op = 0.0f;
#pragma unroll
        for (int jj = 0; jj < 16; ++jj) {
            float Sv = S[jj] * dec[jj];
            Sv = fmaf(sa, bv[jj], Sv);
            Sv = fmaf(vi, kv[jj], Sv);
            S[jj] = Sv;
            op = fmaf(Sv, rv[jj], op);
        }
        op += __shfl_xor(op, 1);
        op += __shfl_xor(op, 2);
        if (q == 0) ob[rowbase + (size_t)t * Dd + i] = f2bf(op);

        if (t + 1 < Tt) {
            sh[c ^ 1][g][j] = l0;
            if (tid < 128) sh[c ^ 1][4 + g][j] = l1;
        }
        __syncthreads();
        c ^= 1;
    }
}

// ---------------- GroupNorm + bonus + gate ----------------
__global__ __launch_bounds__(256)
void gn_kernel(const u16* __restrict__ ob, const u16* __restrict__ rb,
               const u16* __restrict__ kb, const u16* __restrict__ vb,
               const u16* __restrict__ gb,
               const float* __restrict__ gn_w, const float* __restrict__ gn_b,
               const float* __restrict__ r_k, u16* __restrict__ o2)
{
    const int m = blockIdx.x;
    const int tid = threadIdx.x;
    const int c0 = tid * 4;
    const int h = tid >> 4;
    const int jh = c0 & 63;
    const size_t base = (size_t)m * Dd + c0;

    u16x4s ov4 = *(const u16x4s*)(ob + base);
    u16x4s rv4 = *(const u16x4s*)(rb + base);
    u16x4s kv4 = *(const u16x4s*)(kb + base);
    u16x4s vv4 = *(const u16x4s*)(vb + base);
    u16x4s gv4 = *(const u16x4s*)(gb + base);
    float4 rkc = *(const float4*)(r_k + h * 64 + jh);

    float ovv[4] = {bf2f(ov4.x), bf2f(ov4.y), bf2f(ov4.z), bf2f(ov4.w)};
    float rv[4] = {bf2f(rv4.x), bf2f(rv4.y), bf2f(rv4.z), bf2f(rv4.w)};
    float kv[4] = {bf2f(kv4.x), bf2f(kv4.y), bf2f(kv4.z), bf2f(kv4.w)};
    float vv[4] = {bf2f(vv4.x), bf2f(vv4.y), bf2f(vv4.z), bf2f(vv4.w)};
    float gv[4] = {bf2f(gv4.x), bf2f(gv4.y), bf2f(gv4.z), bf2f(gv4.w)};
    float rk4[4] = {rkc.x, rkc.y, rkc.z, rkc.w};

    float s1 = ovv[0] + ovv[1] + ovv[2] + ovv[3];
    float s2 = ovv[0]*ovv[0] + ovv[1]*ovv[1] + ovv[2]*ovv[2] + ovv[3]*ovv[3];
    float sb = rv[0]*kv[0]*rk4[0] + rv[1]*kv[1]*rk4[1] + rv[2]*kv[2]*rk4[2] + rv[3]*kv[3]*rk4[3];
#pragma unroll
    for (int mask = 1; mask < 16; mask <<= 1) {
        s1 += __shfl_xor(s1, mask);
        s2 += __shfl_xor(s2, mask);
        sb += __shfl_xor(sb, mask);
    }
    float mu = s1 * (1.0f / 64.0f);
    float var = s2 * (1.0f / 64.0f) - mu * mu;
    float rstd = rsqrtf(var + 6.4e-4f);

    float4 gwv = *(const float4*)(gn_w + c0);
    float4 gbv = *(const float4*)(gn_b + c0);
    float gw4[4] = {gwv.x, gwv.y, gwv.z, gwv.w};
    float gb4[4] = {gbv.x, gbv.y, gbv.z, gbv.w};

    u16x4s outv; u16* op = &outv.x;
#pragma unroll
    for (int l = 0; l < 4; ++l) {
        float v = (((ovv[l] - mu) * rstd) * gw4[l] + gb4[l] + sb * vv[l]) * gv[l];
        op[l] = f2bf(v);
    }
    *(u16x4s*)(o2 + base) = outv;
}

__global__ __launch_bounds__(256)
void zero_kernel(float* __restrict__ p, int n)
{
    int i = blockIdx.x * 256 + threadIdx.x;
    if (i < n) p[i] = 0.0f;
}

__global__ __launch_bounds__(256)
void cls_kernel(const float* __restrict__ hp, const float* __restrict__ Wc,
                const float* __restrict__ bc, float* __restrict__ out)
{
    const int p = blockIdx.x;
    const int b = p >> 1, c = p & 1;
    const int tid = threadIdx.x;
    float partial = 0.0f;
    for (int d = tid; d < Dd; d += 256)
        partial = fmaf(hp[b * Dd + d], Wc[d * 2 + c], partial);
    __shared__ float red[256];
    red[tid] = partial;
    __syncthreads();
    for (int s = 128; s > 0; s >>= 1) {
        if (tid < s) red[tid] += red[tid + s];
        __syncthreads();
    }
    if (tid == 0) out[b * 2 + c] = red[0] + bc[c];
}

extern "C" void kernel_launch(void* const* d_in, const int* in_sizes, int n_in,
                              void* d_out, int out_size, void* d_ws, size_t ws_size,
                              hipStream_t stream)
{
    const float* x    = (const float*)d_in[0];
    const float* x_r  = (const float*)d_in[1];
    const float* x_w  = (const float*)d_in[2];
    const float* x_k  = (const float*)d_in[3];
    const float* x_v  = (const float*)d_in[4];
    const float* x_a  = (const float*)d_in[5];
    const float* x_g  = (const float*)d_in[6];
    const float* W_r  = (const float*)d_in[7];
    const float* W_k  = (const float*)d_in[8];
    const float* W_v  = (const float*)d_in[9];
    const float* W_o  = (const float*)d_in[10];
    const float* w0   = (const float*)d_in[11];
    const float* w1   = (const float*)d_in[12];
    const float* w2   = (const float*)d_in[13];
    const float* a0   = (const float*)d_in[14];
    const float* a1   = (const float*)d_in[15];
    const float* a2   = (const float*)d_in[16];
    const float* g1   = (const float*)d_in[17];
    const float* g2   = (const float*)d_in[18];
    const float* k_k  = (const float*)d_in[19];
    const float* k_a  = (const float*)d_in[20];
    const float* r_k  = (const float*)d_in[21];
    const float* gn_w = (const float*)d_in[22];
    const float* gn_b = (const float*)d_in[23];
    const float* Wcls = (const float*)d_in[24];
    const float* bcls = (const float*)d_in[25];
    float* out = (float*)d_out;

    const size_t MD = (size_t)Mm * Dd;
    char* w = (char*)d_ws;
    u16* S0 = (u16*)w; w += MD * 2;   // xr -> decay -> g
    u16* S1 = (u16*)w; w += MD * 2;   // xk -> a/b
    u16* S2 = (u16*)w; w += MD * 2;   // xv -> kk -> o2
    u16* S3 = (u16*)w; w += MD * 2;   // xw -> r
    u16* S4 = (u16*)w; w += MD * 2;   // xa -> k
    u16* S5 = (u16*)w; w += MD * 2;   // xg -> v
    u16* S6 = (u16*)w; w += MD * 2;   // scan out o
    u16* TW = (u16*)w; w += (size_t)Mm * 64 * 2;
    u16* TA = (u16*)w; w += (size_t)Mm * 64 * 2;
    u16* TG = (u16*)w; w += (size_t)Mm * 160 * 2;
    float* bufH = (float*)w; w += (size_t)Bb * Dd * 4;

    dim3 blk(256);
    dim3 gMix(Mm);
    dim3 gMf(Mm / 128, 1024 / 128);     // (128, 8)
    dim3 g64(Mm / TILE_M, 1);
    dim3 g160(Mm / TILE_M, 3);

    // token-shift mixes (bf16): xr->S0 xk->S1 xv->S2 xw->S3 xa->S4 xg->S5
    mix6_kernel<<<gMix, blk, 0, stream>>>(x, x_r, x_k, x_v, x_w, x_a, x_g,
                                          S0, S1, S2, S3, S4, S5);
    // LoRA stage-1 (consume S3,S4,S5)
    sgemm_small<<<g64,  blk, 0, stream>>>(S3, Dd, w1, 64,  TW, 64,  64,  Dd, 1);
    sgemm_small<<<g64,  blk, 0, stream>>>(S4, Dd, a1, 64,  TA, 64,  64,  Dd, 0);
    sgemm_small<<<g160, blk, 0, stream>>>(S5, Dd, g1, 160, TG, 160, 160, Dd, 2);
    // big projections (MFMA): r->S3, k->S4, v->S5
    gemm_mfma<0, false><<<gMf, blk, 0, stream>>>(S0, Dd, W_r, nullptr, S3, Dd);
    gemm_mfma<0, false><<<gMf, blk, 0, stream>>>(S1, Dd, W_k, nullptr, S4, Dd);
    gemm_mfma<0, false><<<gMf, blk, 0, stream>>>(S2, Dd, W_v, nullptr, S5, Dd);
    // LoRA stage-2 (MFMA): decay->S0, a->S1
    gemm_mfma<3, true><<<gMf, blk, 0, stream>>>(TW, 64, w2, w0, S0, 64);
    gemm_mfma<2, true><<<gMf, blk, 0, stream>>>(TA, 64, a2, a0, S1, 64);
    // kk / k-mod / b : k=S4 in/out, a=S1 in -> b out, kk->S2
    ew_kv_kernel<<<Mm, blk, 0, stream>>>(S4, S1, S2, k_k, k_a);
    // scan: r=S3 d=S0 k=S4 v=S5 kk=S2 b=S1 -> o=S6
    scan_kernel<<<Bb * Hh, blk, 0, stream>>>(S3, S0, S4, S5, S2, S1, S6);
    // gate (MFMA): g -> S0 (decay slot free)
    gemm_mfma<0, false><<<gMf, blk, 0, stream>>>(TG, 160, g2, nullptr, S0, 160);
    // GN + bonus + gate -> o2 = S2 (kk slot free)
    gn_kernel<<<Mm, blk, 0, stream>>>(S6, S3, S4, S5, S0, gn_w, gn_b, r_k, S2);
    // W_o with fused relu-maxpool
    zero_kernel<<<(Bb * Dd + 255) / 256, blk, 0, stream>>>(bufH, Bb * Dd);
    gemm_wo_mfma<<<gMf, blk, 0, stream>>>(S2, W_o, bufH);
    // classifier
    cls_kernel<<<32, blk, 0, stream>>>(bufH, Wcls, bcls, out);
}

// Round 9
// 1941.320 us; speedup vs baseline: 2.6157x; 1.0807x over previous
//
#include <hip/hip_runtime.h>
#include <hip/hip_bf16.h>

typedef unsigned short u16;
typedef unsigned int u32;

#define Bb 16
#define Tt 1024
#define Dd 1024
#define Nn 64
#define Hh 16
#define Mm (Bb*Tt)

#define TILE_M 64
#define TILE_N 64
#define TILE_K 16

typedef float f32x4 __attribute__((ext_vector_type(4)));
typedef short s16x8 __attribute__((ext_vector_type(8)));

struct __align__(8) u16x4s { u16 x, y, z, w; };

__device__ __forceinline__ float bf2f(u16 u) { return __uint_as_float(((u32)u) << 16); }
__device__ __forceinline__ u16 f2bf(float f) {
    __hip_bfloat16 h = __float2bfloat16(f);
    return *reinterpret_cast<u16*>(&h);
}
__device__ __forceinline__ float sigf(float x) { return 1.0f / (1.0f + expf(-x)); }

// ---------------- mix6: token-shift for all six branches, fp32 -> bf16 ----------------
__global__ __launch_bounds__(256)
void mix6_kernel(const float* __restrict__ x,
                 const float* __restrict__ cr, const float* __restrict__ ck,
                 const float* __restrict__ cv, const float* __restrict__ cw,
                 const float* __restrict__ ca, const float* __restrict__ cg,
                 u16* __restrict__ o0, u16* __restrict__ o1, u16* __restrict__ o2,
                 u16* __restrict__ o3, u16* __restrict__ o4, u16* __restrict__ o5)
{
    const int m = blockIdx.x;
    const int c0 = threadIdx.x * 4;
    const size_t base = (size_t)m * Dd + c0;
    float4 xc = *(const float4*)(x + base);
    float4 xp = make_float4(0.f, 0.f, 0.f, 0.f);
    if (m & (Tt - 1)) xp = *(const float4*)(x + base - Dd);
    float dx[4] = {xp.x - xc.x, xp.y - xc.y, xp.z - xc.z, xp.w - xc.w};
    float xv[4] = {xc.x, xc.y, xc.z, xc.w};
    const float* cfs[6] = {cr, ck, cv, cw, ca, cg};
    u16* outs[6] = {o0, o1, o2, o3, o4, o5};
#pragma unroll
    for (int s = 0; s < 6; ++s) {
        float4 cf = *(const float4*)(cfs[s] + c0);
        float c4[4] = {cf.x, cf.y, cf.z, cf.w};
        u16x4s ov;
        u16* op = &ov.x;
#pragma unroll
        for (int l = 0; l < 4; ++l) op[l] = f2bf(fmaf(dx[l], c4[l], xv[l]));
        *(u16x4s*)(outs[s] + base) = ov;
    }
}

// ---------------- small fp32-compute GEMM for LoRA stage-1 (bf16 A, fp32 B) ----------------
__global__ __launch_bounds__(256)
void sgemm_small(const u16* __restrict__ A, int lda,
                 const float* __restrict__ Bw, int ldb,
                 u16* __restrict__ C, int ldc,
                 int N, int K, int act)
{
    __shared__ float As[TILE_K][TILE_M + 1];
    __shared__ float Bs[TILE_K][TILE_N + 1];
    const int tid = threadIdx.x;
    const int tx = tid & 15, ty = tid >> 4;
    const int bm = blockIdx.x * TILE_M;
    const int bn = blockIdx.y * TILE_N;

    float acc[4][4] = {};

    for (int k0 = 0; k0 < K; k0 += TILE_K) {
#pragma unroll
        for (int l = 0; l < 4; ++l) {
            int idx = l * 256 + tid;
            int kk = idx & 15, mm = idx >> 4;
            As[kk][mm] = bf2f(A[(size_t)(bm + mm) * lda + k0 + kk]);
        }
#pragma unroll
        for (int l = 0; l < 4; ++l) {
            int idx = l * 256 + tid;
            int nn = idx & 63, kk = idx >> 6;
            int gn = bn + nn;
            Bs[kk][nn] = (gn < N) ? Bw[(size_t)(k0 + kk) * ldb + gn] : 0.0f;
        }
        __syncthreads();
#pragma unroll
        for (int kk = 0; kk < TILE_K; ++kk) {
            float af[4], bf[4];
#pragma unroll
            for (int i = 0; i < 4; ++i) af[i] = As[kk][ty * 4 + i];
#pragma unroll
            for (int j = 0; j < 4; ++j) bf[j] = Bs[kk][tx * 4 + j];
#pragma unroll
            for (int i = 0; i < 4; ++i)
#pragma unroll
                for (int j = 0; j < 4; ++j)
                    acc[i][j] = fmaf(af[i], bf[j], acc[i][j]);
        }
        __syncthreads();
    }

#pragma unroll
    for (int i = 0; i < 4; ++i) {
        int gm = bm + ty * 4 + i;
#pragma unroll
        for (int j = 0; j < 4; ++j) {
            int gn = bn + tx * 4 + j;
            if (gn >= N) continue;
            float v = acc[i][j];
            if (act == 1) v = tanhf(v);
            else if (act == 2) v = sigf(v);
            C[(size_t)gm * ldc + gn] = f2bf(v);
        }
    }
}

// ---------------- MFMA GEMM ----------------
template<int ACT, bool HAS_BIAS>
__global__ __launch_bounds__(256)
void gemm_mfma(const u16* __restrict__ A, int lda,
               const float* __restrict__ W,
               const float* __restrict__ bias,
               u16* __restrict__ C, int K)
{
    __shared__ u16 As[128][40];
    __shared__ u16 Bs[128][40];
    const int tid = threadIdx.x;
    const int bm = blockIdx.x * 128, bn = blockIdx.y * 128;
    const int lane = tid & 63, w = tid >> 6;
    const int wr = w >> 1, wc = w & 1;
    const int lr = lane & 15, kg = lane >> 4;

    f32x4 acc[4][4];
#pragma unroll
    for (int m = 0; m < 4; ++m)
#pragma unroll
        for (int n = 0; n < 4; ++n) acc[m][n] = (f32x4){0.f, 0.f, 0.f, 0.f};

    for (int k0 = 0; k0 < K; k0 += 32) {
        {
            int row = tid >> 2, part = tid & 3;
            *(s16x8*)&As[row][part * 8] =
                *(const s16x8*)(A + (size_t)(bm + row) * lda + k0 + part * 8);
            row += 64;
            *(s16x8*)&As[row][part * 8] =
                *(const s16x8*)(A + (size_t)(bm + row) * lda + k0 + part * 8);
        }
        {
            int n4 = (tid & 31) * 4;
            int kp = tid >> 5;
#pragma unroll
            for (int it = 0; it < 2; ++it) {
                int k = 2 * (kp + it * 8);
                const float* wp = W + (size_t)(k0 + k) * 1024 + bn + n4;
                float4 wa = *(const float4*)wp;
                float4 wb = *(const float4*)(wp + 1024);
                *(u32*)&Bs[n4 + 0][k] = (u32)f2bf(wa.x) | ((u32)f2bf(wb.x) << 16);
                *(u32*)&Bs[n4 + 1][k] = (u32)f2bf(wa.y) | ((u32)f2bf(wb.y) << 16);
                *(u32*)&Bs[n4 + 2][k] = (u32)f2bf(wa.z) | ((u32)f2bf(wb.z) << 16);
                *(u32*)&Bs[n4 + 3][k] = (u32)f2bf(wa.w) | ((u32)f2bf(wb.w) << 16);
            }
        }
        __syncthreads();
        s16x8 af[4], bfr[4];
#pragma unroll
        for (int m = 0; m < 4; ++m)
            af[m] = *(const s16x8*)&As[wr * 64 + m * 16 + lr][kg * 8];
#pragma unroll
        for (int n = 0; n < 4; ++n)
            bfr[n] = *(const s16x8*)&Bs[wc * 64 + n * 16 + lr][kg * 8];
#pragma unroll
        for (int m = 0; m < 4; ++m)
#pragma unroll
            for (int n = 0; n < 4; ++n)
                acc[m][n] = __builtin_amdgcn_mfma_f32_16x16x32_bf16(af[m], bfr[n], acc[m][n], 0, 0, 0);
        __syncthreads();
    }

#pragma unroll
    for (int n = 0; n < 4; ++n) {
        int col = bn + wc * 64 + n * 16 + lr;
        float bv = HAS_BIAS ? bias[col] : 0.0f;
#pragma unroll
        for (int m = 0; m < 4; ++m) {
            int row0 = bm + wr * 64 + m * 16 + kg * 4;
#pragma unroll
            for (int r = 0; r < 4; ++r) {
                float v = acc[m][n][r] + bv;
                if (ACT == 2) v = sigf(v);
                else if (ACT == 3) {
                    float ww = -log1pf(expf(-v)) - 0.5f;
                    v = expf(-expf(ww));
                }
                C[(size_t)(row0 + r) * 1024 + col] = f2bf(v);
            }
        }
    }
}

// ---------------- W_o MFMA GEMM with fused relu-colmax -> atomicMax ----------------
__global__ __launch_bounds__(256)
void gemm_wo_mfma(const u16* __restrict__ A,
                  const float* __restrict__ W,
                  float* __restrict__ Hbuf)
{
    __shared__ u16 As[128][40];
    __shared__ u16 Bs[128][40];
    const int tid = threadIdx.x;
    const int bm = blockIdx.x * 128, bn = blockIdx.y * 128;
    const int lane = tid & 63, w = tid >> 6;
    const int wr = w >> 1, wc = w & 1;
    const int lr = lane & 15, kg = lane >> 4;

    f32x4 acc[4][4];
#pragma unroll
    for (int m = 0; m < 4; ++m)
#pragma unroll
        for (int n = 0; n < 4; ++n) acc[m][n] = (f32x4){0.f, 0.f, 0.f, 0.f};

    for (int k0 = 0; k0 < 1024; k0 += 32) {
        {
            int row = tid >> 2, part = tid & 3;
            *(s16x8*)&As[row][part * 8] =
                *(const s16x8*)(A + (size_t)(bm + row) * 1024 + k0 + part * 8);
            row += 64;
            *(s16x8*)&As[row][part * 8] =
                *(const s16x8*)(A + (size_t)(bm + row) * 1024 + k0 + part * 8);
        }
        {
            int n4 = (tid & 31) * 4;
            int kp = tid >> 5;
#pragma unroll
            for (int it = 0; it < 2; ++it) {
                int k = 2 * (kp + it * 8);
                const float* wp = W + (size_t)(k0 + k) * 1024 + bn + n4;
                float4 wa = *(const float4*)wp;
                float4 wb = *(const float4*)(wp + 1024);
                *(u32*)&Bs[n4 + 0][k] = (u32)f2bf(wa.x) | ((u32)f2bf(wb.x) << 16);
                *(u32*)&Bs[n4 + 1][k] = (u32)f2bf(wa.y) | ((u32)f2bf(wb.y) << 16);
                *(u32*)&Bs[n4 + 2][k] = (u32)f2bf(wa.z) | ((u32)f2bf(wb.z) << 16);
                *(u32*)&Bs[n4 + 3][k] = (u32)f2bf(wa.w) | ((u32)f2bf(wb.w) << 16);
            }
        }
        __syncthreads();
        s16x8 af[4], bfr[4];
#pragma unroll
        for (int m = 0; m < 4; ++m)
            af[m] = *(const s16x8*)&As[wr * 64 + m * 16 + lr][kg * 8];
#pragma unroll
        for (int n = 0; n < 4; ++n)
            bfr[n] = *(const s16x8*)&Bs[wc * 64 + n * 16 + lr][kg * 8];
#pragma unroll
        for (int m = 0; m < 4; ++m)
#pragma unroll
            for (int n = 0; n < 4; ++n)
                acc[m][n] = __builtin_amdgcn_mfma_f32_16x16x32_bf16(af[m], bfr[n], acc[m][n], 0, 0, 0);
        __syncthreads();
    }

    const int b = bm >> 10;
#pragma unroll
    for (int n = 0; n < 4; ++n) {
        float mv = -1e30f;
#pragma unroll
        for (int m = 0; m < 4; ++m)
#pragma unroll
            for (int r = 0; r < 4; ++r) mv = fmaxf(mv, acc[m][n][r]);
        mv = fmaxf(mv, __shfl_xor(mv, 16));
        mv = fmaxf(mv, __shfl_xor(mv, 32));
        mv = fmaxf(mv, 0.0f);
        if (lane < 16) {
            int col = bn + wc * 64 + n * 16 + lr;
            atomicMax((u32*)&Hbuf[b * Dd + col], __float_as_uint(mv));
        }
    }
}

// ---------------- kk / k-mod / b ----------------
__global__ __launch_bounds__(256)
void ew_kv_kernel(u16* __restrict__ kbuf, u16* __restrict__ abuf,
                  u16* __restrict__ kkbuf,
                  const float* __restrict__ k_k, const float* __restrict__ k_a)
{
    const int m = blockIdx.x;
    const int tid = threadIdx.x;
    const int c0 = tid * 4;
    const size_t base = (size_t)m * Dd + c0;
    u16x4s kv4 = *(const u16x4s*)(kbuf + base);
    u16x4s av4 = *(const u16x4s*)(abuf + base);
    float4 kkc = *(const float4*)(k_k + c0);
    float4 kac = *(const float4*)(k_a + c0);

    float kin[4] = {bf2f(kv4.x), bf2f(kv4.y), bf2f(kv4.z), bf2f(kv4.w)};
    float ain[4] = {bf2f(av4.x), bf2f(av4.y), bf2f(av4.z), bf2f(av4.w)};
    float kkc4[4] = {kkc.x, kkc.y, kkc.z, kkc.w};
    float kac4[4] = {kac.x, kac.y, kac.z, kac.w};

    float kr[4];
#pragma unroll
    for (int l = 0; l < 4; ++l) kr[l] = kin[l] * kkc4[l];
    float ss = kr[0]*kr[0] + kr[1]*kr[1] + kr[2]*kr[2] + kr[3]*kr[3];
#pragma unroll
    for (int mask = 1; mask < 16; mask <<= 1) ss += __shfl_xor(ss, mask);
    float inv = 1.0f / fmaxf(sqrtf(ss), 1e-12f);

    u16x4s kkv, kmv, bvv;
    u16* kkp = &kkv.x; u16* kmp = &kmv.x; u16* bvp = &bvv.x;
#pragma unroll
    for (int l = 0; l < 4; ++l) {
        float kkf = kr[l] * inv;
        kkp[l] = f2bf(kkf);
        kmp[l] = f2bf(kin[l] * (1.0f + (ain[l] - 1.0f) * kac4[l]));
        bvp[l] = f2bf(kkf * ain[l]);
    }
    *(u16x4s*)(kkbuf + base) = kkv;
    *(u16x4s*)(kbuf  + base) = kmv;
    *(u16x4s*)(abuf  + base) = bvv;
}

// ---------------- RWKV7 scan: barrier-free, per-wave private staging ----------------
// Block = one (b,h). 4 waves; wave w owns rows [16w,16w+16). Lane (il,q): il=lane>>2
// owns S[16w+il][16q..16q+16). Each wave stages all 6 step-vectors into its own LDS
// buffer (lane j handles element j) -> no __syncthreads anywhere. Prefetch depth 2.
__global__ __launch_bounds__(256)
void scan_kernel(const u16* __restrict__ rb, const u16* __restrict__ db,
                 const u16* __restrict__ kb, const u16* __restrict__ vb,
                 const u16* __restrict__ kkb, const u16* __restrict__ bvb,
                 u16* __restrict__ ob)
{
    const int blk = blockIdx.x;
    const int batch = blk >> 4, head = blk & 15;
    const int tid = threadIdx.x;
    const int w = tid >> 6;
    const int lane = tid & 63;
    const int q = lane & 3, il = lane >> 2;
    const int i = w * 16 + il;          // global row in [0,64)
    const int j0 = q * 16;

    __shared__ float ws[4][2][6][64];   // per-wave double-buffered vectors (12 KB)

    const size_t rowbase = (size_t)batch * Tt * Dd + head * Nn;

    float S[16];
#pragma unroll
    for (int jj = 0; jj < 16; ++jj) S[jj] = 0.0f;

    // stage t=0 (each lane: element j=lane of all 6 vectors)
    {
        size_t off = rowbase + lane;
        ws[w][0][0][lane] = bf2f(rb[off]);
        ws[w][0][1][lane] = bf2f(db[off]);
        ws[w][0][2][lane] = bf2f(kb[off]);
        ws[w][0][3][lane] = bf2f(vb[off]);
        ws[w][0][4][lane] = bf2f(kkb[off]);
        ws[w][0][5][lane] = bf2f(bvb[off]);
    }
    // prefetch t=1 into registers
    u16 p0 = 0, p1 = 0, p2 = 0, p3 = 0, p4 = 0, p5 = 0;
    {
        size_t off = rowbase + Dd + lane;
        p0 = rb[off]; p1 = db[off]; p2 = kb[off];
        p3 = vb[off]; p4 = kkb[off]; p5 = bvb[off];
    }

    int c = 0;
    for (int t = 0; t < Tt; ++t) {
        // write prefetched t+1 vectors into the other buffer (same-wave, no barrier)
        if (t + 1 < Tt) {
            ws[w][c ^ 1][0][lane] = bf2f(p0);
            ws[w][c ^ 1][1][lane] = bf2f(p1);
            ws[w][c ^ 1][2][lane] = bf2f(p2);
            ws[w][c ^ 1][3][lane] = bf2f(p3);
            ws[w][c ^ 1][4][lane] = bf2f(p4);
            ws[w][c ^ 1][5][lane] = bf2f(p5);
        }
        // issue t+2 loads (fly during this step's compute)
        if (t + 2 < Tt) {
            size_t off = rowbase + (size_t)(t + 2) * Dd + lane;
            p0 = rb[off]; p1 = db[off]; p2 = kb[off];
            p3 = vb[off]; p4 = kkb[off]; p5 = bvb[off];
        }

        float rv[16], dec[16], kv[16], kkv[16], bv[16];
#pragma unroll
        for (int u = 0; u < 4; ++u) {
            *(float4*)&rv[u*4]  = *(const float4*)&ws[w][c][0][j0 + u*4];
            *(float4*)&dec[u*4] = *(const float4*)&ws[w][c][1][j0 + u*4];
            *(float4*)&kv[u*4]  = *(const float4*)&ws[w][c][2][j0 + u*4];
            *(float4*)&kkv[u*4] = *(const float4*)&ws[w][c][4][j0 + u*4];
            *(float4*)&bv[u*4]  = *(const float4*)&ws[w][c][5][j0 + u*4];
        }
        float vi = ws[w][c][3][i];

        float sa = 0.0f;
#pragma unroll
        for (int jj = 0; jj < 16; ++jj) sa = fmaf(S[jj], kkv[jj], sa);
        sa = -sa;
        sa += __shfl_xor(sa, 1);
        sa += __shfl_xor(sa, 2);

        float op = 0.0f;
#pragma unroll
        for (int jj = 0; jj < 16; ++jj) {
            float Sv = S[jj] * dec[jj];
            Sv = fmaf(sa, bv[jj], Sv);
            Sv = fmaf(vi, kv[jj], Sv);
            S[jj] = Sv;
            op = fmaf(Sv, rv[jj], op);
        }
        op += __shfl_xor(op, 1);
        op += __shfl_xor(op, 2);
        if (q == 0) ob[rowbase + (size_t)t * Dd + i] = f2bf(op);

        c ^= 1;
    }
}

// ---------------- GroupNorm + bonus + gate ----------------
__global__ __launch_bounds__(256)
void gn_kernel(const u16* __restrict__ ob, const u16* __restrict__ rb,
               const u16* __restrict__ kb, const u16* __restrict__ vb,
               const u16* __restrict__ gb,
               const float* __restrict__ gn_w, const float* __restrict__ gn_b,
               const float* __restrict__ r_k, u16* __restrict__ o2)
{
    const int m = blockIdx.x;
    const int tid = threadIdx.x;
    const int c0 = tid * 4;
    const int h = tid >> 4;
    const int jh = c0 & 63;
    const size_t base = (size_t)m * Dd + c0;

    u16x4s ov4 = *(const u16x4s*)(ob + base);
    u16x4s rv4 = *(const u16x4s*)(rb + base);
    u16x4s kv4 = *(const u16x4s*)(kb + base);
    u16x4s vv4 = *(const u16x4s*)(vb + base);
    u16x4s gv4 = *(const u16x4s*)(gb + base);
    float4 rkc = *(const float4*)(r_k + h * 64 + jh);

    float ovv[4] = {bf2f(ov4.x), bf2f(ov4.y), bf2f(ov4.z), bf2f(ov4.w)};
    float rv[4] = {bf2f(rv4.x), bf2f(rv4.y), bf2f(rv4.z), bf2f(rv4.w)};
    float kv[4] = {bf2f(kv4.x), bf2f(kv4.y), bf2f(kv4.z), bf2f(kv4.w)};
    float vv[4] = {bf2f(vv4.x), bf2f(vv4.y), bf2f(vv4.z), bf2f(vv4.w)};
    float gv[4] = {bf2f(gv4.x), bf2f(gv4.y), bf2f(gv4.z), bf2f(gv4.w)};
    float rk4[4] = {rkc.x, rkc.y, rkc.z, rkc.w};

    float s1 = ovv[0] + ovv[1] + ovv[2] + ovv[3];
    float s2 = ovv[0]*ovv[0] + ovv[1]*ovv[1] + ovv[2]*ovv[2] + ovv[3]*ovv[3];
    float sb = rv[0]*kv[0]*rk4[0] + rv[1]*kv[1]*rk4[1] + rv[2]*kv[2]*rk4[2] + rv[3]*kv[3]*rk4[3];
#pragma unroll
    for (int mask = 1; mask < 16; mask <<= 1) {
        s1 += __shfl_xor(s1, mask);
        s2 += __shfl_xor(s2, mask);
        sb += __shfl_xor(sb, mask);
    }
    float mu = s1 * (1.0f / 64.0f);
    float var = s2 * (1.0f / 64.0f) - mu * mu;
    float rstd = rsqrtf(var + 6.4e-4f);

    float4 gwv = *(const float4*)(gn_w + c0);
    float4 gbv = *(const float4*)(gn_b + c0);
    float gw4[4] = {gwv.x, gwv.y, gwv.z, gwv.w};
    float gb4[4] = {gbv.x, gbv.y, gbv.z, gbv.w};

    u16x4s outv; u16* op = &outv.x;
#pragma unroll
    for (int l = 0; l < 4; ++l) {
        float v = (((ovv[l] - mu) * rstd) * gw4[l] + gb4[l] + sb * vv[l]) * gv[l];
        op[l] = f2bf(v);
    }
    *(u16x4s*)(o2 + base) = outv;
}

__global__ __launch_bounds__(256)
void zero_kernel(float* __restrict__ p, int n)
{
    int i = blockIdx.x * 256 + threadIdx.x;
    if (i < n) p[i] = 0.0f;
}

__global__ __launch_bounds__(256)
void cls_kernel(const float* __restrict__ hp, const float* __restrict__ Wc,
                const float* __restrict__ bc, float* __restrict__ out)
{
    const int p = blockIdx.x;
    const int b = p >> 1, c = p & 1;
    const int tid = threadIdx.x;
    float partial = 0.0f;
    for (int d = tid; d < Dd; d += 256)
        partial = fmaf(hp[b * Dd + d], Wc[d * 2 + c], partial);
    __shared__ float red[256];
    red[tid] = partial;
    __syncthreads();
    for (int s = 128; s > 0; s >>= 1) {
        if (tid < s) red[tid] += red[tid + s];
        __syncthreads();
    }
    if (tid == 0) out[b * 2 + c] = red[0] + bc[c];
}

extern "C" void kernel_launch(void* const* d_in, const int* in_sizes, int n_in,
                              void* d_out, int out_size, void* d_ws, size_t ws_size,
                              hipStream_t stream)
{
    const float* x    = (const float*)d_in[0];
    const float* x_r  = (const float*)d_in[1];
    const float* x_w  = (const float*)d_in[2];
    const float* x_k  = (const float*)d_in[3];
    const float* x_v  = (const float*)d_in[4];
    const float* x_a  = (const float*)d_in[5];
    const float* x_g  = (const float*)d_in[6];
    const float* W_r  = (const float*)d_in[7];
    const float* W_k  = (const float*)d_in[8];
    const float* W_v  = (const float*)d_in[9];
    const float* W_o  = (const float*)d_in[10];
    const float* w0   = (const float*)d_in[11];
    const float* w1   = (const float*)d_in[12];
    const float* w2   = (const float*)d_in[13];
    const float* a0   = (const float*)d_in[14];
    const float* a1   = (const float*)d_in[15];
    const float* a2   = (const float*)d_in[16];
    const float* g1   = (const float*)d_in[17];
    const float* g2   = (const float*)d_in[18];
    const float* k_k  = (const float*)d_in[19];
    const float* k_a  = (const float*)d_in[20];
    const float* r_k  = (const float*)d_in[21];
    const float* gn_w = (const float*)d_in[22];
    const float* gn_b = (const float*)d_in[23];
    const float* Wcls = (const float*)d_in[24];
    const float* bcls = (const float*)d_in[25];
    float* out = (float*)d_out;

    const size_t MD = (size_t)Mm * Dd;
    char* w = (char*)d_ws;
    u16* S0 = (u16*)w; w += MD * 2;   // xr -> decay -> g
    u16* S1 = (u16*)w; w += MD * 2;   // xk -> a/b
    u16* S2 = (u16*)w; w += MD * 2;   // xv -> kk -> o2
    u16* S3 = (u16*)w; w += MD * 2;   // xw -> r
    u16* S4 = (u16*)w; w += MD * 2;   // xa -> k
    u16* S5 = (u16*)w; w += MD * 2;   // xg -> v
    u16* S6 = (u16*)w; w += MD * 2;   // scan out o
    u16* TW = (u16*)w; w += (size_t)Mm * 64 * 2;
    u16* TA = (u16*)w; w += (size_t)Mm * 64 * 2;
    u16* TG = (u16*)w; w += (size_t)Mm * 160 * 2;
    float* bufH = (float*)w; w += (size_t)Bb * Dd * 4;

    dim3 blk(256);
    dim3 gMix(Mm);
    dim3 gMf(Mm / 128, 1024 / 128);
    dim3 g64(Mm / TILE_M, 1);
    dim3 g160(Mm / TILE_M, 3);

    mix6_kernel<<<gMix, blk, 0, stream>>>(x, x_r, x_k, x_v, x_w, x_a, x_g,
                                          S0, S1, S2, S3, S4, S5);
    sgemm_small<<<g64,  blk, 0, stream>>>(S3, Dd, w1, 64,  TW, 64,  64,  Dd, 1);
    sgemm_small<<<g64,  blk, 0, stream>>>(S4, Dd, a1, 64,  TA, 64,  64,  Dd, 0);
    sgemm_small<<<g160, blk, 0, stream>>>(S5, Dd, g1, 160, TG, 160, 160, Dd, 2);
    gemm_mfma<0, false><<<gMf, blk, 0, stream>>>(S0, Dd, W_r, nullptr, S3, Dd);
    gemm_mfma<0, false><<<gMf, blk, 0, stream>>>(S1, Dd, W_k, nullptr, S4, Dd);
    gemm_mfma<0, false><<<gMf, blk, 0, stream>>>(S2, Dd, W_v, nullptr, S5, Dd);
    gemm_mfma<3, true><<<gMf, blk, 0, stream>>>(TW, 64, w2, w0, S0, 64);
    gemm_mfma<2, true><<<gMf, blk, 0, stream>>>(TA, 64, a2, a0, S1, 64);
    ew_kv_kernel<<<Mm, blk, 0, stream>>>(S4, S1, S2, k_k, k_a);
    scan_kernel<<<Bb * Hh, blk, 0, stream>>>(S3, S0, S4, S5, S2, S1, S6);
    gemm_mfma<0, false><<<gMf, blk, 0, stream>>>(TG, 160, g2, nullptr, S0, 160);
    gn_kernel<<<Mm, blk, 0, stream>>>(S6, S3, S4, S5, S0, gn_w, gn_b, r_k, S2);
    zero_kernel<<<(Bb * Dd + 255) / 256, blk, 0, stream>>>(bufH, Bb * Dd);
    gemm_wo_mfma<<<gMf, blk, 0, stream>>>(S2, W_o, bufH);
    cls_kernel<<<32, blk, 0, stream>>>(bufH, Wcls, bcls, out);
}